// Round 6
// baseline (940.977 us; speedup 1.0000x reference)
//
#include <hip/hip_runtime.h>
#include <stdint.h>

typedef unsigned long long u64;

#define BB   4
#define CC   4
#define HHH  512
#define WWW  512
#define HW   (HHH*WWW)        /* 262144 = 2^18 */
#define NIMG (BB*CC)          /* 16 */
#define NSRC 2
#define NLVL 5
#define KTOP 64
#define NBIN 4096             /* histogram bins; sizes > NBIN go to the large list (<=63 of them) */
#define HSZ  512              /* LDS root-dedup hash (max distinct roots per 1024-px block = 512) */
#define WPI  4096             /* 64-bit words per image (512 rows * 8) */

// ---------------- union-find (min-root == min pixel index) ----------------
// unite()'s convergence test uses ONLY atomic return values; path-halving plain
// stores always write a valid ancestor (chain values are monotone decreasing).

__device__ __forceinline__ int findRoot(int* L, int i) {
  int p = L[i];
  while (p != i) {
    int gp = L[p];
    L[i] = gp;          // path halving; benign race
    i = gp;
    p = L[i];
  }
  return i;
}

__device__ __forceinline__ void unite(int* L, int a, int b) {
  bool done = false;
  do {
    a = findRoot(L, a);
    b = findRoot(L, b);
    if (a < b) {
      int old = atomicMin(&L[b], a);
      done = (old == b);
      b = old;
    } else if (b < a) {
      int old = atomicMin(&L[a], b);
      done = (old == a);
      a = old;
    } else {
      done = true;
    }
  } while (!done);
}

// run start bit (within 64-px segment) for a pixel at bit k of word w
__device__ __forceinline__ int runstart_bit(u64 w, int k) {
  u64 lowz = ~w & ((k == 0) ? 0ull : ((1ull << k) - 1));
  return lowz ? (64 - __clzll(lowz)) : 0;   // highest zero below k, +1
}

// ---------------- masks (bitmaps: 1 bit/px, u64 words, [src][img][4096]) ----

__global__ void k_base_mask_bits(const float* __restrict__ pred, const int* __restrict__ tgt,
                                 u64* __restrict__ bm) {
  int i = blockIdx.x * blockDim.x + threadIdx.x;   // over BB*HW, waves = 64 consecutive px
  if (i >= BB * HW) return;
  int b  = i >> 18;
  int hw = i & (HW - 1);
  float p0 = pred[(b * CC + 0) * HW + hw];
  float p1 = pred[(b * CC + 1) * HW + hw];
  float p2 = pred[(b * CC + 2) * HW + hw];
  float p3 = pred[(b * CC + 3) * HW + hw];
  int amax = 0; float best = p0;
  if (p1 > best) { best = p1; amax = 1; }
  if (p2 > best) { best = p2; amax = 2; }
  if (p3 > best) { best = p3; amax = 3; }
  int tg = tgt[i];
  int lane = threadIdx.x & 63;
  u64* bp = bm;                         // src 0 (predictions)
  u64* bt = bm + (size_t)NIMG * WPI;    // src 1 (targets)
#pragma unroll
  for (int c = 0; c < CC; ++c) {
    u64 wp = __ballot(amax == c);
    u64 wt = __ballot(tg == c);
    if (lane == 0) {
      int wi = ((b * CC + c) << 12) + (hw >> 6);
      bp[wi] = wp;
      bt[wi] = wt;
    }
  }
}

// 3x3 box morphology on bitmaps, zero padding. One thread per output word.
__global__ void k_morph_bits(const u64* __restrict__ in, u64* __restrict__ out, int erode) {
  int t = blockIdx.x * blockDim.x + threadIdx.x;   // over NSRC*NIMG*WPI = 131072
  if (t >= NSRC * NIMG * WPI) return;
  int word = t & (WPI - 1);
  int row = word >> 3, wc = word & 7;
  const u64* ip = in + (t - word);                 // image base
  u64 c0 = ip[word];
  u64 cm = wc ? ip[word - 1] : 0;
  u64 cp = (wc < 7) ? ip[word + 1] : 0;
  u64 u0 = 0, um = 0, up_ = 0, d0 = 0, dm = 0, dp = 0;
  if (row) {
    u0 = ip[word - 8];
    um = wc ? ip[word - 9] : 0;
    up_ = (wc < 7) ? ip[word - 7] : 0;
  }
  if (row < HHH - 1) {
    d0 = ip[word + 8];
    dm = wc ? ip[word + 7] : 0;
    dp = (wc < 7) ? ip[word + 9] : 0;
  }
  u64 v, vm, vp, r;
  if (erode) {
    v = u0 & c0 & d0; vm = um & cm & dm; vp = up_ & cp & dp;
    r = v & ((v << 1) | (vm >> 63)) & ((v >> 1) | (vp << 63));
  } else {
    v = u0 | c0 | d0; vm = um | cm | dm; vp = up_ | cp | dp;
    r = v | (v << 1) | (vm >> 63) | (v >> 1) | (vp << 63);
  }
  out[t] = r;
}

// ---------------- CCL ----------------

// Per-pixel init: fuses zeroing of counts/hist/lcount (coalesced, replaces the
// 16MB memset) and writes labels ONLY at run-head bits (label = own index).
__global__ void k_runinit_bits(const u64* __restrict__ bm, int* __restrict__ labels,
                               int* __restrict__ counts, int* __restrict__ hist,
                               int* __restrict__ lcount) {
  int g = blockIdx.x * blockDim.x + threadIdx.x;   // over NIMG*HW
  if (g >= NIMG * HW) return;
  counts[g] = 0;
  if (g < NIMG * NBIN) hist[g] = 0;
  if (g < NIMG) lcount[g] = 0;
  u64 w = bm[g >> 6];                              // broadcast within wave
  int lane = threadIdx.x & 63;
  u64 hm = w & ~(w << 1);                          // segment-fragmented run heads
  if ((hm >> lane) & 1) {
    int hw = g & (HW - 1);
    labels[g] = hw;                                // labels indexed per-image == g here
  }
}

// Wave-parallel merge: one WAVE per word, one LANE per need-bit. The wave
// broadcast-loads the 4 words, computes the vertical need mask once
// (need = r0 & up & ~(ls(r0) & ls(up)) -> unite only where not implied by the
// left column), then each set bit's unite runs on its own lane (one unite per
// thread -> latency hidden by 64x more waves; fixes the 1.3%-occupancy
// straggler serialization of the per-word version).
__global__ void k_merge_bits(const u64* __restrict__ bm, int* __restrict__ labels) {
  int gid = blockIdx.x * blockDim.x + threadIdx.x;
  int wid = gid >> 6;                              // word index over NIMG*WPI
  if (wid >= NIMG * WPI) return;
  int lane = threadIdx.x & 63;
  u64 r0 = bm[wid];
  if (!r0) return;
  int word = wid & (WPI - 1);
  int row = word >> 3, wc = word & 7;
  int* L = labels + ((wid >> 12) << 18);
  int segbase = (row << 9) + (wc << 6);
  u64 prev = wc ? bm[wid - 1] : 0;
  if (lane == 0 && (r0 & 1) && (prev >> 63))       // cross-word horizontal
    unite(L, segbase, segbase - 64 + runstart_bit(prev, 63));
  if (row) {
    u64 up = bm[wid - 8];
    if (up) {
      u64 upprev = wc ? bm[wid - 9] : 0;
      u64 lsr0 = (r0 << 1) | (prev >> 63);
      u64 lsup = (up << 1) | (upprev >> 63);
      u64 need = r0 & up & ~(lsr0 & lsup);
      if ((need >> lane) & 1) {
        int a = segbase + runstart_bit(r0, lane);
        int b = segbase - 512 + runstart_bit(up, lane);
        unite(L, a, b);
      }
    }
  }
}

// Fused flatten+count: wave reads one broadcast word; head lanes (from bit
// pattern) walk the chain read-only, compute run length from bits, dedupe
// roots through an LDS hash, then one global atomic per distinct root/block.
__global__ void k_flatten_count(const u64* __restrict__ bm, const int* __restrict__ labels,
                                int* __restrict__ counts) {
  __shared__ int hk[HSZ];
  __shared__ int hv[HSZ];
  int t = threadIdx.x;                             // 1024
  if (t < HSZ) { hk[t] = -1; hv[t] = 0; }
  __syncthreads();
  int g = blockIdx.x * 1024 + t;                   // pixel id over NIMG*HW
  int lane = t & 63;
  u64 w = bm[g >> 6];                              // broadcast
  const int* L = labels + ((g >> 18) << 18);
  int hw = g & (HW - 1);
  u64 hm = w & ~(w << 1);
  if ((hm >> lane) & 1) {
    u64 inv = ~(w >> lane);
    int len = inv ? (__ffsll(inv) - 1) : (64 - lane);
    int r = hw;                                    // read-only root walk
    int q = L[r];
    while (q != r) { r = q; q = L[r]; }
    unsigned h = ((unsigned)r * 2654435761u >> 16) & (HSZ - 1);
    for (;;) {                                     // linear probe; table holds worst case
      int prevk = atomicCAS(&hk[h], -1, r);
      if (prevk == -1 || prevk == r) { atomicAdd(&hv[h], len); break; }
      h = (h + 1) & (HSZ - 1);
    }
  }
  __syncthreads();
  int imgbase = (blockIdx.x * 1024) & ~(HW - 1);   // blocks never straddle images
  if (t < HSZ && hk[t] != -1)
    atomicAdd(&counts[imgbase + hk[t]], hv[t]);
}

// histogram of sizes <= NBIN (LDS -> 4096-bin global hist);
// sizes > NBIN (at most 63 per image) appended to a compact per-image list.
__global__ void k_ccl_hist(const int* __restrict__ counts, int* __restrict__ hist,
                           int* __restrict__ lcount, int* __restrict__ lsizes) {
  __shared__ int lh[NBIN];
  int t = threadIdx.x;                             // 1024 threads
  for (int b = t; b < NBIN; b += 1024) lh[b] = 0;
  __syncthreads();
  int base = blockIdx.x * 16384;                   // 16 blocks per image
  int img = base >> 18;
#pragma unroll
  for (int j = 0; j < 16; ++j) {
    int s = counts[base + t + j * 1024];
    if (s > 0) {
      if (s <= NBIN) atomicAdd(&lh[s - 1], 1);
      else {
        int idx = atomicAdd(&lcount[img], 1);
        if (idx < KTOP) lsizes[img * KTOP + idx] = s;
      }
    }
  }
  __syncthreads();
  int* gh = hist + img * NBIN;
  for (int b = t; b < NBIN; b += 1024)
    if (lh[b]) atomicAdd(&gh[b], lh[b]);
}

// sorted top-64: rank-sort the large list (all > NBIN), then suffix-walk the
// 4096-bin LDS-resident histogram to fill the remaining slots.
__global__ void k_top64(const int* __restrict__ hist, const int* __restrict__ lcount,
                        const int* __restrict__ lsizes, float* __restrict__ top) {
  __shared__ int lh[NBIN];
  __shared__ int ls[KTOP];
  __shared__ int sc[256];
  int img = blockIdx.x;
  int t = threadIdx.x;                             // 256
  const int* gh = hist + img * NBIN;
  for (int k = t; k < NBIN; k += 256) lh[k] = gh[k];
  int n = lcount[img];
  if (n > KTOP) n = KTOP;
  if (t < KTOP) ls[t] = (t < n) ? lsizes[img * KTOP + t] : 0;
  float* tp = top + (size_t)img * KTOP;
  if (t < KTOP) tp[t] = 0.f;
  __syncthreads();
  if (t < n) {                                     // rank-sort descending (n <= 63)
    int myv = ls[t], rank = 0;
    for (int j = 0; j < n; ++j) {
      int vj = ls[j];
      rank += (vj > myv) || (vj == myv && j < t);
    }
    tp[rank] = (float)myv;
  }
  int base = NBIN - 16 * (t + 1);                  // descending chunks of 16 bins
  int c = 0;
#pragma unroll
  for (int k = 0; k < 16; ++k) c += lh[base + k];
  sc[t] = c;
  __syncthreads();
  for (int off = 1; off < 256; off <<= 1) {        // Hillis-Steele inclusive scan
    int v = (t >= off) ? sc[t - off] : 0;
    __syncthreads();
    sc[t] += v;
    __syncthreads();
  }
  int pos = n + sc[t] - c;                         // components ranked before my chunk
  if (pos < KTOP && c > 0) {
    for (int k = 15; k >= 0 && pos < KTOP; --k) {
      int s = base + k + 1;
      int hc = lh[base + k];
      while (hc-- > 0 && pos < KTOP) tp[pos++] = (float)s;
    }
  }
}

// loss[b] = sum over {lvl, c, k} |topP - topT| ; top layout [src][lvl][img][KTOP]
__global__ void k_loss(const float* __restrict__ top, float* __restrict__ out) {
  int b = blockIdx.x;
  int t = threadIdx.x;                             // 256
  float acc = 0.f;
  const int TOT = NLVL * CC * KTOP;                // 1280
  for (int e = t; e < TOT; e += 256) {
    int k = e & (KTOP - 1);
    int rest = e >> 6;
    int c = rest & (CC - 1);
    int lvl = rest >> 2;
    int img = b * CC + c;
    size_t iP = ((size_t)(0 * NLVL + lvl) * NIMG + img) * KTOP + k;
    size_t iT = ((size_t)(1 * NLVL + lvl) * NIMG + img) * KTOP + k;
    acc += fabsf(top[iP] - top[iT]);
  }
  __shared__ float r[256];
  r[t] = acc;
  __syncthreads();
  for (int off = 128; off > 0; off >>= 1) {
    if (t < off) r[t] += r[t + off];
    __syncthreads();
  }
  if (t == 0) out[b] = r[0];
}

// ---------------- driver ----------------

static inline void run_rounds(const u64* bmbuf, int lvl, int* labels, int* counts,
                              int* hist, int* lcount, int* lsizes, float* top,
                              hipStream_t stream) {
  const int NW = NIMG * WPI;                       // 65536 words per src
  const int N  = NIMG * HW;                        // 4.19M pixels
  for (int src = 0; src < NSRC; ++src) {
    const u64* m = bmbuf + (size_t)src * NW;
    k_runinit_bits <<<N / 256, 256, 0, stream>>>(m, labels, counts, hist, lcount);
    k_merge_bits   <<<N / 256, 256, 0, stream>>>(m, labels);   // one wave per word
    k_flatten_count<<<N / 1024, 1024, 0, stream>>>(m, labels, counts);
    k_ccl_hist     <<<N / 16384, 1024, 0, stream>>>(counts, hist, lcount, lsizes);
    k_top64        <<<NIMG, 256, 0, stream>>>(hist, lcount, lsizes,
                                              top + (size_t)(src * NLVL + lvl) * NIMG * KTOP);
  }
}

extern "C" void kernel_launch(void* const* d_in, const int* in_sizes, int n_in,
                              void* d_out, int out_size, void* d_ws, size_t ws_size,
                              hipStream_t stream) {
  const float* pred = (const float*)d_in[0];
  const int*   tgt  = (const int*)d_in[1];
  float* out = (float*)d_out;

  uint8_t* ws = (uint8_t*)d_ws;
  size_t off = 0;
  u64* bmbase = (u64*)(ws + off); off += (size_t)NSRC * NIMG * WPI * 8;   // 1 MB, level 2
  u64* bmA    = (u64*)(ws + off); off += (size_t)NSRC * NIMG * WPI * 8;   // 1 MB
  u64* bmB    = (u64*)(ws + off); off += (size_t)NSRC * NIMG * WPI * 8;   // 1 MB
  int* labels = (int*)(ws + off); off += (size_t)NIMG * HW * 4;           // 16 MB
  int* counts = (int*)(ws + off); off += (size_t)NIMG * HW * 4;           // 16 MB
  int* hist   = (int*)(ws + off); off += (size_t)NIMG * NBIN * 4;         // 256 KB
  int* lcount = (int*)(ws + off); off += (size_t)NIMG * 4;
  int* lsizes = (int*)(ws + off); off += (size_t)NIMG * KTOP * 4;
  float* top  = (float*)(ws + off); off += (size_t)NSRC * NLVL * NIMG * KTOP * 4;

  const int MW = NSRC * NIMG * WPI;                // morphology words (131072)

  // base one-hot bitmaps (level 2)
  k_base_mask_bits<<<(BB * HW) / 256, 256, 0, stream>>>(pred, tgt, bmbase);
  run_rounds(bmbase, 2, labels, counts, hist, lcount, lsizes, top, stream);

  // erosion chain: level 3, 4
  k_morph_bits<<<MW / 256, 256, 0, stream>>>(bmbase, bmA, 1);
  run_rounds(bmA, 3, labels, counts, hist, lcount, lsizes, top, stream);
  k_morph_bits<<<MW / 256, 256, 0, stream>>>(bmA, bmB, 1);
  run_rounds(bmB, 4, labels, counts, hist, lcount, lsizes, top, stream);

  // dilation chain: level 1, 0
  k_morph_bits<<<MW / 256, 256, 0, stream>>>(bmbase, bmA, 0);
  run_rounds(bmA, 1, labels, counts, hist, lcount, lsizes, top, stream);
  k_morph_bits<<<MW / 256, 256, 0, stream>>>(bmA, bmB, 0);
  run_rounds(bmB, 0, labels, counts, hist, lcount, lsizes, top, stream);

  k_loss<<<BB, 256, 0, stream>>>(top, out);
}

// Round 7
// 721.794 us; speedup vs baseline: 1.3037x; 1.3037x over previous
//
#include <hip/hip_runtime.h>
#include <stdint.h>

typedef unsigned long long u64;

#define BB   4
#define CC   4
#define HHH  512
#define WWW  512
#define HW   (HHH*WWW)        /* 262144 = 2^18 */
#define NIMG (BB*CC)          /* 16 */
#define NSRC 2
#define NLVL 5
#define KTOP 64
#define NBIN 4096             /* histogram bins; sizes > NBIN go to the large list (<=63 of them) */
#define HSZ  512              /* LDS root-dedup hash */
#define WPI  4096             /* 64-bit words per image (512 rows * 8) */
#define TROWS 64              /* tile = 64 rows x 512 cols */
#define TPX  (TROWS*WWW)      /* 32768 px per tile */
#define TWORDS (TROWS*8)      /* 512 words per tile */
#define NTILE 8               /* tiles per image */

// ---------------- union-find (min-root == min pixel index) ----------------
// Convergence test uses ONLY atomic return values; path-halving plain stores
// always write a valid ancestor (values monotone decreasing).

__device__ __forceinline__ int findRoot(int* L, int i) {
  int p = L[i];
  while (p != i) {
    int gp = L[p];
    L[i] = gp;          // path halving; benign race
    i = gp;
    p = L[i];
  }
  return i;
}

__device__ __forceinline__ void unite(int* L, int a, int b) {
  bool done = false;
  do {
    a = findRoot(L, a);
    b = findRoot(L, b);
    if (a < b) {
      int old = atomicMin(&L[b], a);
      done = (old == b);
      b = old;
    } else if (b < a) {
      int old = atomicMin(&L[a], b);
      done = (old == a);
      a = old;
    } else {
      done = true;
    }
  } while (!done);
}

// run start bit (within 64-px segment) for a pixel at bit k of word w
__device__ __forceinline__ int runstart_bit(u64 w, int k) {
  u64 lowz = ~w & ((k == 0) ? 0ull : ((1ull << k) - 1));
  return lowz ? (64 - __clzll(lowz)) : 0;   // highest zero below k, +1
}

// ---------------- masks (bitmaps: 1 bit/px, u64 words, [src][img][4096]) ----

__global__ void k_base_mask_bits(const float* __restrict__ pred, const int* __restrict__ tgt,
                                 u64* __restrict__ bm) {
  int i = blockIdx.x * blockDim.x + threadIdx.x;   // over BB*HW
  if (i >= BB * HW) return;
  int b  = i >> 18;
  int hw = i & (HW - 1);
  float p0 = pred[(b * CC + 0) * HW + hw];
  float p1 = pred[(b * CC + 1) * HW + hw];
  float p2 = pred[(b * CC + 2) * HW + hw];
  float p3 = pred[(b * CC + 3) * HW + hw];
  int amax = 0; float best = p0;
  if (p1 > best) { best = p1; amax = 1; }
  if (p2 > best) { best = p2; amax = 2; }
  if (p3 > best) { best = p3; amax = 3; }
  int tg = tgt[i];
  int lane = threadIdx.x & 63;
  u64* bp = bm;
  u64* bt = bm + (size_t)NIMG * WPI;
#pragma unroll
  for (int c = 0; c < CC; ++c) {
    u64 wp = __ballot(amax == c);
    u64 wt = __ballot(tg == c);
    if (lane == 0) {
      int wi = ((b * CC + c) << 12) + (hw >> 6);
      bp[wi] = wp;
      bt[wi] = wt;
    }
  }
}

// 3x3 box morphology on bitmaps, zero padding. One thread per output word.
__global__ void k_morph_bits(const u64* __restrict__ in, u64* __restrict__ out, int erode) {
  int t = blockIdx.x * blockDim.x + threadIdx.x;   // over NSRC*NIMG*WPI
  if (t >= NSRC * NIMG * WPI) return;
  int word = t & (WPI - 1);
  int row = word >> 3, wc = word & 7;
  const u64* ip = in + (t - word);
  u64 c0 = ip[word];
  u64 cm = wc ? ip[word - 1] : 0;
  u64 cp = (wc < 7) ? ip[word + 1] : 0;
  u64 u0 = 0, um = 0, up_ = 0, d0 = 0, dm = 0, dp = 0;
  if (row) {
    u0 = ip[word - 8];
    um = wc ? ip[word - 9] : 0;
    up_ = (wc < 7) ? ip[word - 7] : 0;
  }
  if (row < HHH - 1) {
    d0 = ip[word + 8];
    dm = wc ? ip[word + 7] : 0;
    dp = (wc < 7) ? ip[word + 9] : 0;
  }
  u64 v, vm, vp, r;
  if (erode) {
    v = u0 & c0 & d0; vm = um & cm & dm; vp = up_ & cp & dp;
    r = v & ((v << 1) | (vm >> 63)) & ((v >> 1) | (vp << 63));
  } else {
    v = u0 | c0 | d0; vm = um | cm | dm; vp = up_ | cp | dp;
    r = v | (v << 1) | (vm >> 63) | (v >> 1) | (vp << 63);
  }
  out[t] = r;
}

// ---------------- CCL phase A: per-tile union-find entirely in LDS ----------

__global__ __launch_bounds__(1024) void k_ccl_tile(const u64* __restrict__ bm,
                                                   int* __restrict__ labels,
                                                   int* __restrict__ counts,
                                                   int* __restrict__ hist,
                                                   int* __restrict__ lcount) {
  __shared__ int par[TPX];          // 128 KB
  __shared__ u64 w[TWORDS];         // 4 KB
  __shared__ int anyfg;
  int t = threadIdx.x;              // 1024
  int tile = blockIdx.x;            // NIMG*NTILE = 128
  int img = tile >> 3;
  int trow0 = (tile & 7) * TROWS;
  const u64* ib = bm + ((size_t)img << 12);
  if (t == 0) anyfg = 0;
  __syncthreads();
  if (t < TWORDS) {
    u64 wd = ib[trow0 * 8 + t];
    w[t] = wd;
    if (wd) atomicOr(&anyfg, 1);
  }
  // fused zeroing: counts (tile range), hist slice, lcount
  int4* c4 = (int4*)(counts + (img << 18) + trow0 * WWW);
  for (int k = t; k < TPX / 4; k += 1024) c4[k] = make_int4(0, 0, 0, 0);
  for (int k = t; k < (NIMG * NBIN) / 128; k += 1024)
    hist[tile * ((NIMG * NBIN) / 128) + k] = 0;
  if (t == 0 && tile < NIMG) lcount[tile] = 0;
  __syncthreads();
  if (!anyfg) return;               // empty tile (erosion levels): nothing to label
  // init: every fg px points at its segment-run head; bg points at itself
  for (int p = t; p < TPX; p += 1024) {
    u64 wd = w[p >> 6];
    int k = p & 63;
    par[p] = ((wd >> k) & 1) ? ((p & ~63) + runstart_bit(wd, k)) : p;
  }
  __syncthreads();
  // intra-tile unites: one wave per word, one lane per need-bit (LDS atomics)
  int wave = t >> 6, lane = t & 63;
  for (int i = wave; i < TWORDS; i += 16) {
    u64 r0 = w[i];
    if (!r0) continue;
    int row = i >> 3, wc = i & 7;
    int segbase = (row << 9) + (wc << 6);
    u64 prev = wc ? w[i - 1] : 0;
    if (lane == 0 && (r0 & 1) && (prev >> 63))
      unite(par, segbase, segbase - 64 + runstart_bit(prev, 63));
    if (row) {
      u64 up = w[i - 8];
      if (up) {
        u64 upprev = wc ? w[i - 9] : 0;
        u64 lsr0 = (r0 << 1) | (prev >> 63);
        u64 lsup = (up << 1) | (upprev >> 63);
        u64 need = r0 & up & ~(lsr0 & lsup);
        if ((need >> lane) & 1)
          unite(par, segbase + runstart_bit(r0, lane),
                     segbase - 512 + runstart_bit(up, lane));
      }
    }
  }
  __syncthreads();
  // local flatten: read-only walk + store to OWN entry (stores are roots ->
  // concurrent walkers reading them still see valid ancestors)
  for (int p = t; p < TPX; p += 1024) {
    int r = par[p];
    int q = par[r];
    while (q != r) { r = q; q = par[r]; }
    par[p] = r;
  }
  __syncthreads();
  // publish image-local roots (coalesced)
  int* lb = labels + (img << 18) + trow0 * WWW;
  int off = trow0 * WWW;
  for (int p = t; p < TPX; p += 1024) lb[p] = off + par[p];
}

// ---------------- CCL phase B: global unites across the 7 row-seams ---------

__global__ void k_seam_merge(const u64* __restrict__ bm, int* __restrict__ labels) {
  int gid = blockIdx.x * blockDim.x + threadIdx.x;
  int sw = gid >> 6;                 // seam-word id over NIMG*7*8
  if (sw >= NIMG * 7 * 8) return;
  int lane = threadIdx.x & 63;
  int img = sw / 56;
  int rem = sw - img * 56;
  int seam = rem >> 3, wc = rem & 7;
  int rowb = (seam + 1) * TROWS;     // top row of the lower tile
  const u64* ib = bm + ((size_t)img << 12);
  int wb = rowb * 8 + wc;
  u64 r0 = ib[wb];
  if (!r0) return;
  u64 up = ib[wb - 8];
  if (!up) return;
  u64 prev = wc ? ib[wb - 1] : 0;
  u64 upprev = wc ? ib[wb - 9] : 0;
  u64 lsr0 = (r0 << 1) | (prev >> 63);
  u64 lsup = (up << 1) | (upprev >> 63);
  u64 need = r0 & up & ~(lsr0 & lsup);
  if ((need >> lane) & 1) {
    int* L = labels + (img << 18);
    int pb = (rowb << 9) + (wc << 6) + lane;
    unite(L, L[pb], L[pb - 512]);    // endpoints jump straight to tile roots
  }
}

// Fused flatten+count: wave reads one broadcast word; head lanes walk the
// (now near-flat) chain read-only, run length from bits, LDS-hash dedupe,
// one global atomic per distinct root per block.
__global__ void k_flatten_count(const u64* __restrict__ bm, const int* __restrict__ labels,
                                int* __restrict__ counts) {
  __shared__ int hk[HSZ];
  __shared__ int hv[HSZ];
  int t = threadIdx.x;               // 1024
  if (t < HSZ) { hk[t] = -1; hv[t] = 0; }
  __syncthreads();
  int g = blockIdx.x * 1024 + t;     // pixel id over NIMG*HW
  int lane = t & 63;
  u64 w = bm[g >> 6];
  const int* L = labels + ((g >> 18) << 18);
  int hw = g & (HW - 1);
  u64 hm = w & ~(w << 1);
  if ((hm >> lane) & 1) {
    u64 inv = ~(w >> lane);
    int len = inv ? (__ffsll(inv) - 1) : (64 - lane);
    int r = hw;                      // read-only root walk
    int q = L[r];
    while (q != r) { r = q; q = L[r]; }
    unsigned h = ((unsigned)r * 2654435761u >> 16) & (HSZ - 1);
    for (;;) {
      int prevk = atomicCAS(&hk[h], -1, r);
      if (prevk == -1 || prevk == r) { atomicAdd(&hv[h], len); break; }
      h = (h + 1) & (HSZ - 1);
    }
  }
  __syncthreads();
  int imgbase = (blockIdx.x * 1024) & ~(HW - 1);
  if (t < HSZ && hk[t] != -1)
    atomicAdd(&counts[imgbase + hk[t]], hv[t]);
}

// histogram of sizes <= NBIN (LDS -> 4096-bin global hist);
// sizes > NBIN (at most 63 per image) appended to a compact per-image list.
__global__ void k_ccl_hist(const int* __restrict__ counts, int* __restrict__ hist,
                           int* __restrict__ lcount, int* __restrict__ lsizes) {
  __shared__ int lh[NBIN];
  int t = threadIdx.x;               // 1024
  for (int b = t; b < NBIN; b += 1024) lh[b] = 0;
  __syncthreads();
  int base = blockIdx.x * 16384;     // 16 blocks per image
  int img = base >> 18;
#pragma unroll
  for (int j = 0; j < 16; ++j) {
    int s = counts[base + t + j * 1024];
    if (s > 0) {
      if (s <= NBIN) atomicAdd(&lh[s - 1], 1);
      else {
        int idx = atomicAdd(&lcount[img], 1);
        if (idx < KTOP) lsizes[img * KTOP + idx] = s;
      }
    }
  }
  __syncthreads();
  int* gh = hist + img * NBIN;
  for (int b = t; b < NBIN; b += 1024)
    if (lh[b]) atomicAdd(&gh[b], lh[b]);
}

// sorted top-64: rank-sort the large list (all > NBIN), then suffix-walk the
// 4096-bin LDS-resident histogram to fill the remaining slots.
__global__ void k_top64(const int* __restrict__ hist, const int* __restrict__ lcount,
                        const int* __restrict__ lsizes, float* __restrict__ top) {
  __shared__ int lh[NBIN];
  __shared__ int ls[KTOP];
  __shared__ int sc[256];
  int img = blockIdx.x;
  int t = threadIdx.x;               // 256
  const int* gh = hist + img * NBIN;
  for (int k = t; k < NBIN; k += 256) lh[k] = gh[k];
  int n = lcount[img];
  if (n > KTOP) n = KTOP;
  if (t < KTOP) ls[t] = (t < n) ? lsizes[img * KTOP + t] : 0;
  float* tp = top + (size_t)img * KTOP;
  if (t < KTOP) tp[t] = 0.f;
  __syncthreads();
  if (t < n) {                       // rank-sort descending (n <= 63)
    int myv = ls[t], rank = 0;
    for (int j = 0; j < n; ++j) {
      int vj = ls[j];
      rank += (vj > myv) || (vj == myv && j < t);
    }
    tp[rank] = (float)myv;
  }
  int base = NBIN - 16 * (t + 1);    // descending chunks of 16 bins
  int c = 0;
#pragma unroll
  for (int k = 0; k < 16; ++k) c += lh[base + k];
  sc[t] = c;
  __syncthreads();
  for (int off = 1; off < 256; off <<= 1) {
    int v = (t >= off) ? sc[t - off] : 0;
    __syncthreads();
    sc[t] += v;
    __syncthreads();
  }
  int pos = n + sc[t] - c;
  if (pos < KTOP && c > 0) {
    for (int k = 15; k >= 0 && pos < KTOP; --k) {
      int s = base + k + 1;
      int hc = lh[base + k];
      while (hc-- > 0 && pos < KTOP) tp[pos++] = (float)s;
    }
  }
}

// loss[b] = sum over {lvl, c, k} |topP - topT| ; top layout [src][lvl][img][KTOP]
__global__ void k_loss(const float* __restrict__ top, float* __restrict__ out) {
  int b = blockIdx.x;
  int t = threadIdx.x;               // 256
  float acc = 0.f;
  const int TOT = NLVL * CC * KTOP;  // 1280
  for (int e = t; e < TOT; e += 256) {
    int k = e & (KTOP - 1);
    int rest = e >> 6;
    int c = rest & (CC - 1);
    int lvl = rest >> 2;
    int img = b * CC + c;
    size_t iP = ((size_t)(0 * NLVL + lvl) * NIMG + img) * KTOP + k;
    size_t iT = ((size_t)(1 * NLVL + lvl) * NIMG + img) * KTOP + k;
    acc += fabsf(top[iP] - top[iT]);
  }
  __shared__ float r[256];
  r[t] = acc;
  __syncthreads();
  for (int off = 128; off > 0; off >>= 1) {
    if (t < off) r[t] += r[t + off];
    __syncthreads();
  }
  if (t == 0) out[b] = r[0];
}

// ---------------- driver ----------------

static inline void run_rounds(const u64* bmbuf, int lvl, int* labels, int* counts,
                              int* hist, int* lcount, int* lsizes, float* top,
                              hipStream_t stream) {
  const int NW = NIMG * WPI;
  const int N  = NIMG * HW;
  for (int src = 0; src < NSRC; ++src) {
    const u64* m = bmbuf + (size_t)src * NW;
    k_ccl_tile     <<<NIMG * NTILE, 1024, 0, stream>>>(m, labels, counts, hist, lcount);
    k_seam_merge   <<<(NIMG * 7 * 8 * 64) / 256, 256, 0, stream>>>(m, labels);
    k_flatten_count<<<N / 1024, 1024, 0, stream>>>(m, labels, counts);
    k_ccl_hist     <<<N / 16384, 1024, 0, stream>>>(counts, hist, lcount, lsizes);
    k_top64        <<<NIMG, 256, 0, stream>>>(hist, lcount, lsizes,
                                              top + (size_t)(src * NLVL + lvl) * NIMG * KTOP);
  }
}

extern "C" void kernel_launch(void* const* d_in, const int* in_sizes, int n_in,
                              void* d_out, int out_size, void* d_ws, size_t ws_size,
                              hipStream_t stream) {
  const float* pred = (const float*)d_in[0];
  const int*   tgt  = (const int*)d_in[1];
  float* out = (float*)d_out;

  uint8_t* ws = (uint8_t*)d_ws;
  size_t off = 0;
  u64* bmbase = (u64*)(ws + off); off += (size_t)NSRC * NIMG * WPI * 8;   // 1 MB
  u64* bmA    = (u64*)(ws + off); off += (size_t)NSRC * NIMG * WPI * 8;   // 1 MB
  u64* bmB    = (u64*)(ws + off); off += (size_t)NSRC * NIMG * WPI * 8;   // 1 MB
  int* labels = (int*)(ws + off); off += (size_t)NIMG * HW * 4;           // 16 MB
  int* counts = (int*)(ws + off); off += (size_t)NIMG * HW * 4;           // 16 MB
  int* hist   = (int*)(ws + off); off += (size_t)NIMG * NBIN * 4;         // 256 KB
  int* lcount = (int*)(ws + off); off += (size_t)NIMG * 4;
  int* lsizes = (int*)(ws + off); off += (size_t)NIMG * KTOP * 4;
  float* top  = (float*)(ws + off); off += (size_t)NSRC * NLVL * NIMG * KTOP * 4;

  const int MW = NSRC * NIMG * WPI;  // morphology words (131072)

  // base one-hot bitmaps (level 2)
  k_base_mask_bits<<<(BB * HW) / 256, 256, 0, stream>>>(pred, tgt, bmbase);
  run_rounds(bmbase, 2, labels, counts, hist, lcount, lsizes, top, stream);

  // erosion chain: level 3, 4
  k_morph_bits<<<MW / 256, 256, 0, stream>>>(bmbase, bmA, 1);
  run_rounds(bmA, 3, labels, counts, hist, lcount, lsizes, top, stream);
  k_morph_bits<<<MW / 256, 256, 0, stream>>>(bmA, bmB, 1);
  run_rounds(bmB, 4, labels, counts, hist, lcount, lsizes, top, stream);

  // dilation chain: level 1, 0
  k_morph_bits<<<MW / 256, 256, 0, stream>>>(bmbase, bmA, 0);
  run_rounds(bmA, 1, labels, counts, hist, lcount, lsizes, top, stream);
  k_morph_bits<<<MW / 256, 256, 0, stream>>>(bmA, bmB, 0);
  run_rounds(bmB, 0, labels, counts, hist, lcount, lsizes, top, stream);

  k_loss<<<BB, 256, 0, stream>>>(top, out);
}

// Round 8
// 592.345 us; speedup vs baseline: 1.5886x; 1.2185x over previous
//
#include <hip/hip_runtime.h>
#include <stdint.h>

typedef unsigned long long u64;

#define BB   4
#define CC   4
#define HHH  512
#define WWW  512
#define HW   (HHH*WWW)        /* 262144 = 2^18 */
#define NIMG (BB*CC)          /* 16 */
#define NSRC 2
#define NLVL 5
#define KTOP 64
#define NBIN 4096             /* histogram bins; sizes > NBIN go to the large list */
#define HSZ  512              /* LDS root-dedup hash (max distinct roots per 1024-px block = 512) */
#define WPI  4096             /* 64-bit words per image (512 rows * 8) */
#define TROWS 32              /* tile = 32 rows x 512 cols -> 64 KB par, 2 blocks/CU */
#define TPX  (TROWS*WWW)      /* 16384 px per tile */
#define TWORDS (TROWS*8)      /* 256 words per tile */
#define NTILE 16              /* tiles per image */
#define NSEAM (NTILE-1)       /* 15 row-seams per image */

// ---------------- union-find (min-root == min pixel index) ----------------
// Convergence test uses ONLY atomic return values; path-halving plain stores
// always write a valid ancestor (values monotone decreasing).

__device__ __forceinline__ void unite(int* L, int a, int b) {
  // inline findRoot twice per iteration
  bool done = false;
  do {
    { int p = L[a]; while (p != a) { int gp = L[p]; L[a] = gp; a = gp; p = L[a]; } }
    { int p = L[b]; while (p != b) { int gp = L[p]; L[b] = gp; b = gp; p = L[b]; } }
    if (a < b) {
      int old = atomicMin(&L[b], a);
      done = (old == b);
      b = old;
    } else if (b < a) {
      int old = atomicMin(&L[a], b);
      done = (old == a);
      a = old;
    } else {
      done = true;
    }
  } while (!done);
}

// run start bit (within 64-px segment) for a pixel at bit k of word w
__device__ __forceinline__ int runstart_bit(u64 w, int k) {
  u64 lowz = ~w & ((k == 0) ? 0ull : ((1ull << k) - 1));
  return lowz ? (64 - __clzll(lowz)) : 0;   // highest zero below k, +1
}

// ---------------- masks (bitmaps: 1 bit/px, u64 words, [src][img][4096]) ----

__global__ void k_base_mask_bits(const float* __restrict__ pred, const int* __restrict__ tgt,
                                 u64* __restrict__ bm) {
  int i = blockIdx.x * blockDim.x + threadIdx.x;   // over BB*HW
  if (i >= BB * HW) return;
  int b  = i >> 18;
  int hw = i & (HW - 1);
  float p0 = pred[(b * CC + 0) * HW + hw];
  float p1 = pred[(b * CC + 1) * HW + hw];
  float p2 = pred[(b * CC + 2) * HW + hw];
  float p3 = pred[(b * CC + 3) * HW + hw];
  int amax = 0; float best = p0;
  if (p1 > best) { best = p1; amax = 1; }
  if (p2 > best) { best = p2; amax = 2; }
  if (p3 > best) { best = p3; amax = 3; }
  int tg = tgt[i];
  int lane = threadIdx.x & 63;
  u64* bp = bm;
  u64* bt = bm + (size_t)NIMG * WPI;
#pragma unroll
  for (int c = 0; c < CC; ++c) {
    u64 wp = __ballot(amax == c);
    u64 wt = __ballot(tg == c);
    if (lane == 0) {
      int wi = ((b * CC + c) << 12) + (hw >> 6);
      bp[wi] = wp;
      bt[wi] = wt;
    }
  }
}

// 3x3 box morphology on bitmaps, zero padding. One thread per output word.
__global__ void k_morph_bits(const u64* __restrict__ in, u64* __restrict__ out, int erode) {
  int t = blockIdx.x * blockDim.x + threadIdx.x;   // over NSRC*NIMG*WPI
  if (t >= NSRC * NIMG * WPI) return;
  int word = t & (WPI - 1);
  int row = word >> 3, wc = word & 7;
  const u64* ip = in + (t - word);
  u64 c0 = ip[word];
  u64 cm = wc ? ip[word - 1] : 0;
  u64 cp = (wc < 7) ? ip[word + 1] : 0;
  u64 u0 = 0, um = 0, up_ = 0, d0 = 0, dm = 0, dp = 0;
  if (row) {
    u0 = ip[word - 8];
    um = wc ? ip[word - 9] : 0;
    up_ = (wc < 7) ? ip[word - 7] : 0;
  }
  if (row < HHH - 1) {
    d0 = ip[word + 8];
    dm = wc ? ip[word + 7] : 0;
    dp = (wc < 7) ? ip[word + 9] : 0;
  }
  u64 v, vm, vp, r;
  if (erode) {
    v = u0 & c0 & d0; vm = um & cm & dm; vp = up_ & cp & dp;
    r = v & ((v << 1) | (vm >> 63)) & ((v >> 1) | (vp << 63));
  } else {
    v = u0 | c0 | d0; vm = um | cm | dm; vp = up_ | cp | dp;
    r = v | (v << 1) | (vm >> 63) | (v >> 1) | (vp << 63);
  }
  out[t] = r;
}

// ---------------- CCL phase A: per-tile union-find entirely in LDS ----------
// Publishes labels ONLY at run-head pixels (the only entries read downstream).

__global__ __launch_bounds__(1024) void k_ccl_tile(const u64* __restrict__ bm,
                                                   int* __restrict__ labels,
                                                   int* __restrict__ hist,
                                                   int* __restrict__ lcount) {
  __shared__ int par[TPX];          // 64 KB -> 2 blocks/CU
  __shared__ u64 w[TWORDS];         // 2 KB
  __shared__ int anyfg;
  int t = threadIdx.x;              // 1024
  int tile = blockIdx.x;            // NIMG*NTILE = 256
  int img = tile >> 4;
  int trow0 = (tile & 15) * TROWS;
  const u64* ib = bm + ((size_t)img << 12);
  if (t == 0) anyfg = 0;
  __syncthreads();
  if (t < TWORDS) {
    u64 wd = ib[trow0 * 8 + t];
    w[t] = wd;
    if (wd) atomicOr(&anyfg, 1);
  }
  // fused zeroing: hist slice (256 entries/block), lcount
  if (t < 256) hist[tile * 256 + t] = 0;
  if (t == 0 && tile < NIMG) lcount[tile] = 0;
  __syncthreads();
  if (!anyfg) return;               // empty tile: nothing to label
  // init: fg px -> its segment-run head; bg -> self (never read)
  for (int p = t; p < TPX; p += 1024) {
    u64 wd = w[p >> 6];
    int k = p & 63;
    par[p] = ((wd >> k) & 1) ? ((p & ~63) + runstart_bit(wd, k)) : p;
  }
  __syncthreads();
  // intra-tile unites: one wave per word, one lane per need-bit (LDS atomics)
  int wave = t >> 6, lane = t & 63;
  for (int i = wave; i < TWORDS; i += 16) {
    u64 r0 = w[i];
    if (!r0) continue;
    int row = i >> 3, wc = i & 7;
    int segbase = (row << 9) + (wc << 6);
    u64 prev = wc ? w[i - 1] : 0;
    if (lane == 0 && (r0 & 1) && (prev >> 63))
      unite(par, segbase, segbase - 64 + runstart_bit(prev, 63));
    if (row) {
      u64 up = w[i - 8];
      if (up) {
        u64 upprev = wc ? w[i - 9] : 0;
        u64 lsr0 = (r0 << 1) | (prev >> 63);
        u64 lsup = (up << 1) | (upprev >> 63);
        u64 need = r0 & up & ~(lsr0 & lsup);
        if ((need >> lane) & 1)
          unite(par, segbase + runstart_bit(r0, lane),
                     segbase - 512 + runstart_bit(up, lane));
      }
    }
  }
  __syncthreads();
  // flatten + publish HEADS ONLY (read-only walk; store to own global entry)
  int* L = labels + (img << 18) + trow0 * WWW;
  int off = trow0 * WWW;
  for (int i = wave; i < TWORDS; i += 16) {
    u64 wd = w[i];
    if (!wd) continue;
    u64 hm = wd & ~(wd << 1);
    if ((hm >> lane) & 1) {
      int p = ((i >> 3) << 9) + ((i & 7) << 6) + lane;
      int r = par[p];
      int q = par[r];
      while (q != r) { r = q; q = par[r]; }
      L[p] = off + r;
    }
  }
}

// ---------------- CCL phase B: global unites across the 15 row-seams -------
// Endpoints are HEAD indices computed from the bitmap (labels valid there).

__global__ void k_seam_merge(const u64* __restrict__ bm, int* __restrict__ labels) {
  int gid = blockIdx.x * blockDim.x + threadIdx.x;
  int sw = gid >> 6;                 // seam-word id over NIMG*NSEAM*8
  if (sw >= NIMG * NSEAM * 8) return;
  int lane = threadIdx.x & 63;
  int img = sw / (NSEAM * 8);
  int rem = sw - img * (NSEAM * 8);
  int seam = rem >> 3, wc = rem & 7;
  int rowb = (seam + 1) * TROWS;     // top row of the lower tile
  const u64* ib = bm + ((size_t)img << 12);
  int wb = rowb * 8 + wc;
  u64 r0 = ib[wb];
  if (!r0) return;
  u64 up = ib[wb - 8];
  if (!up) return;
  u64 prev = wc ? ib[wb - 1] : 0;
  u64 upprev = wc ? ib[wb - 9] : 0;
  u64 lsr0 = (r0 << 1) | (prev >> 63);
  u64 lsup = (up << 1) | (upprev >> 63);
  u64 need = r0 & up & ~(lsr0 & lsup);
  if ((need >> lane) & 1) {
    int* L = labels + (img << 18);
    int segbase = (rowb << 9) + (wc << 6);
    int ha = segbase + runstart_bit(r0, lane);
    int hb = segbase - 512 + runstart_bit(up, lane);
    unite(L, ha, hb);
  }
}

// Fused flatten+count: head lanes walk the (near-flat) chain read-only,
// run length from bits, LDS-hash dedupe, one global atomic per root/block.
__global__ void k_flatten_count(const u64* __restrict__ bm, const int* __restrict__ labels,
                                int* __restrict__ counts) {
  __shared__ int hk[HSZ];
  __shared__ int hv[HSZ];
  int t = threadIdx.x;               // 1024
  if (t < HSZ) { hk[t] = -1; hv[t] = 0; }
  __syncthreads();
  int g = blockIdx.x * 1024 + t;     // pixel id over NIMG*HW
  int lane = t & 63;
  u64 w = bm[g >> 6];
  const int* L = labels + ((g >> 18) << 18);
  int hw = g & (HW - 1);
  u64 hm = w & ~(w << 1);
  if ((hm >> lane) & 1) {
    u64 inv = ~(w >> lane);
    int len = inv ? (__ffsll(inv) - 1) : (64 - lane);
    int r = hw;                      // read-only root walk from the head
    int q = L[r];
    while (q != r) { r = q; q = L[r]; }
    unsigned h = ((unsigned)r * 2654435761u >> 16) & (HSZ - 1);
    for (;;) {
      int prevk = atomicCAS(&hk[h], -1, r);
      if (prevk == -1 || prevk == r) { atomicAdd(&hv[h], len); break; }
      h = (h + 1) & (HSZ - 1);
    }
  }
  __syncthreads();
  int imgbase = (blockIdx.x * 1024) & ~(HW - 1);
  if (t < HSZ && hk[t] != -1)
    atomicAdd(&counts[imgbase + hk[t]], hv[t]);
}

// Head-gated histogram: counts can be nonzero only at head pixels (roots are
// heads), so read counts only where the bitmap has a head bit, and SELF-RESET
// nonzero entries so the next round inherits a clean counts buffer.
__global__ void k_ccl_hist(const u64* __restrict__ bm, int* __restrict__ counts,
                           int* __restrict__ hist, int* __restrict__ lcount,
                           int* __restrict__ lsizes) {
  __shared__ int lh[NBIN];
  int t = threadIdx.x;               // 1024
  for (int b = t; b < NBIN; b += 1024) lh[b] = 0;
  __syncthreads();
  int base = blockIdx.x * 16384;     // 16 blocks per image
  int img = base >> 18;
  int lane = t & 63;
#pragma unroll
  for (int j = 0; j < 16; ++j) {
    int g = base + t + j * 1024;
    u64 w = bm[g >> 6];
    if (!w) continue;
    u64 hm = w & ~(w << 1);
    if ((hm >> lane) & 1) {
      int s = counts[g];
      if (s > 0) {
        counts[g] = 0;               // self-reset for next round
        if (s <= NBIN) atomicAdd(&lh[s - 1], 1);
        else {
          int idx = atomicAdd(&lcount[img], 1);
          if (idx < KTOP) lsizes[img * KTOP + idx] = s;
        }
      }
    }
  }
  __syncthreads();
  int* gh = hist + img * NBIN;
  for (int b = t; b < NBIN; b += 1024)
    if (lh[b]) atomicAdd(&gh[b], lh[b]);
}

// sorted top-64: rank-sort the large list (all > NBIN), then suffix-walk the
// 4096-bin LDS-resident histogram to fill the remaining slots.
__global__ void k_top64(const int* __restrict__ hist, const int* __restrict__ lcount,
                        const int* __restrict__ lsizes, float* __restrict__ top) {
  __shared__ int lh[NBIN];
  __shared__ int ls[KTOP];
  __shared__ int sc[256];
  int img = blockIdx.x;
  int t = threadIdx.x;               // 256
  const int* gh = hist + img * NBIN;
  for (int k = t; k < NBIN; k += 256) lh[k] = gh[k];
  int n = lcount[img];
  if (n > KTOP) n = KTOP;
  if (t < KTOP) ls[t] = (t < n) ? lsizes[img * KTOP + t] : 0;
  float* tp = top + (size_t)img * KTOP;
  if (t < KTOP) tp[t] = 0.f;
  __syncthreads();
  if (t < n) {                       // rank-sort descending (n <= 63)
    int myv = ls[t], rank = 0;
    for (int j = 0; j < n; ++j) {
      int vj = ls[j];
      rank += (vj > myv) || (vj == myv && j < t);
    }
    tp[rank] = (float)myv;
  }
  int base = NBIN - 16 * (t + 1);    // descending chunks of 16 bins
  int c = 0;
#pragma unroll
  for (int k = 0; k < 16; ++k) c += lh[base + k];
  sc[t] = c;
  __syncthreads();
  for (int off = 1; off < 256; off <<= 1) {
    int v = (t >= off) ? sc[t - off] : 0;
    __syncthreads();
    sc[t] += v;
    __syncthreads();
  }
  int pos = n + sc[t] - c;
  if (pos < KTOP && c > 0) {
    for (int k = 15; k >= 0 && pos < KTOP; --k) {
      int s = base + k + 1;
      int hc = lh[base + k];
      while (hc-- > 0 && pos < KTOP) tp[pos++] = (float)s;
    }
  }
}

// loss[b] = sum over {lvl, c, k} |topP - topT| ; top layout [src][lvl][img][KTOP]
__global__ void k_loss(const float* __restrict__ top, float* __restrict__ out) {
  int b = blockIdx.x;
  int t = threadIdx.x;               // 256
  float acc = 0.f;
  const int TOT = NLVL * CC * KTOP;  // 1280
  for (int e = t; e < TOT; e += 256) {
    int k = e & (KTOP - 1);
    int rest = e >> 6;
    int c = rest & (CC - 1);
    int lvl = rest >> 2;
    int img = b * CC + c;
    size_t iP = ((size_t)(0 * NLVL + lvl) * NIMG + img) * KTOP + k;
    size_t iT = ((size_t)(1 * NLVL + lvl) * NIMG + img) * KTOP + k;
    acc += fabsf(top[iP] - top[iT]);
  }
  __shared__ float r[256];
  r[t] = acc;
  __syncthreads();
  for (int off = 128; off > 0; off >>= 1) {
    if (t < off) r[t] += r[t + off];
    __syncthreads();
  }
  if (t == 0) out[b] = r[0];
}

// ---------------- driver ----------------

static inline void run_rounds(const u64* bmbuf, int lvl, int* labels, int* counts,
                              int* hist, int* lcount, int* lsizes, float* top,
                              hipStream_t stream) {
  const int NW = NIMG * WPI;
  const int N  = NIMG * HW;
  for (int src = 0; src < NSRC; ++src) {
    const u64* m = bmbuf + (size_t)src * NW;
    k_ccl_tile     <<<NIMG * NTILE, 1024, 0, stream>>>(m, labels, hist, lcount);
    k_seam_merge   <<<(NIMG * NSEAM * 8 * 64) / 256, 256, 0, stream>>>(m, labels);
    k_flatten_count<<<N / 1024, 1024, 0, stream>>>(m, labels, counts);
    k_ccl_hist     <<<N / 16384, 1024, 0, stream>>>(m, counts, hist, lcount, lsizes);
    k_top64        <<<NIMG, 256, 0, stream>>>(hist, lcount, lsizes,
                                              top + (size_t)(src * NLVL + lvl) * NIMG * KTOP);
  }
}

extern "C" void kernel_launch(void* const* d_in, const int* in_sizes, int n_in,
                              void* d_out, int out_size, void* d_ws, size_t ws_size,
                              hipStream_t stream) {
  const float* pred = (const float*)d_in[0];
  const int*   tgt  = (const int*)d_in[1];
  float* out = (float*)d_out;

  uint8_t* ws = (uint8_t*)d_ws;
  size_t off = 0;
  u64* bmbase = (u64*)(ws + off); off += (size_t)NSRC * NIMG * WPI * 8;   // 1 MB
  u64* bmA    = (u64*)(ws + off); off += (size_t)NSRC * NIMG * WPI * 8;   // 1 MB
  u64* bmB    = (u64*)(ws + off); off += (size_t)NSRC * NIMG * WPI * 8;   // 1 MB
  int* labels = (int*)(ws + off); off += (size_t)NIMG * HW * 4;           // 16 MB
  int* counts = (int*)(ws + off); off += (size_t)NIMG * HW * 4;           // 16 MB
  int* hist   = (int*)(ws + off); off += (size_t)NIMG * NBIN * 4;         // 256 KB
  int* lcount = (int*)(ws + off); off += (size_t)NIMG * 4;
  int* lsizes = (int*)(ws + off); off += (size_t)NIMG * KTOP * 4;
  float* top  = (float*)(ws + off); off += (size_t)NSRC * NLVL * NIMG * KTOP * 4;

  const int MW = NSRC * NIMG * WPI;  // morphology words (131072)

  // counts must start at zero (ws is poisoned once); hist self-resets it
  // after every round, so one upfront memset per launch suffices.
  hipMemsetAsync(counts, 0, (size_t)NIMG * HW * 4, stream);

  // base one-hot bitmaps (level 2)
  k_base_mask_bits<<<(BB * HW) / 256, 256, 0, stream>>>(pred, tgt, bmbase);
  run_rounds(bmbase, 2, labels, counts, hist, lcount, lsizes, top, stream);

  // erosion chain: level 3, 4
  k_morph_bits<<<MW / 256, 256, 0, stream>>>(bmbase, bmA, 1);
  run_rounds(bmA, 3, labels, counts, hist, lcount, lsizes, top, stream);
  k_morph_bits<<<MW / 256, 256, 0, stream>>>(bmA, bmB, 1);
  run_rounds(bmB, 4, labels, counts, hist, lcount, lsizes, top, stream);

  // dilation chain: level 1, 0
  k_morph_bits<<<MW / 256, 256, 0, stream>>>(bmbase, bmA, 0);
  run_rounds(bmA, 1, labels, counts, hist, lcount, lsizes, top, stream);
  k_morph_bits<<<MW / 256, 256, 0, stream>>>(bmA, bmB, 0);
  run_rounds(bmB, 0, labels, counts, hist, lcount, lsizes, top, stream);

  k_loss<<<BB, 256, 0, stream>>>(top, out);
}

// Round 9
// 372.111 us; speedup vs baseline: 2.5288x; 1.5919x over previous
//
#include <hip/hip_runtime.h>
#include <stdint.h>

typedef unsigned long long u64;

#define BB   4
#define CC   4
#define HHH  512
#define WWW  512
#define HW   (HHH*WWW)        /* 262144 = 2^18 */
#define NIMG (BB*CC)          /* 16 */
#define NSRC 2
#define NLVL 5
#define NB   (NLVL*NIMG)      /* 80 images per src batch */
#define KTOP 64
#define NBIN 4096             /* histogram bins; sizes > NBIN go to the large list */
#define HSZ  512              /* LDS root-dedup hash (max heads per 1024-px block = 512) */
#define WPI  4096             /* 64-bit words per image (512 rows * 8) */
#define TROWS 32              /* tile = 32 rows x 512 cols -> 64 KB par, 2 blocks/CU */
#define TPX  (TROWS*WWW)      /* 16384 px per tile */
#define TWORDS (TROWS*8)      /* 256 words per tile */
#define NTILE 16              /* tiles per image */
#define NSEAM (NTILE-1)       /* 15 row-seams per image */

// ---------------- union-find (min-root == min pixel index) ----------------
// Convergence test uses ONLY atomic return values; path-halving plain stores
// always write a valid ancestor (values monotone decreasing).

__device__ __forceinline__ void unite(int* L, int a, int b) {
  bool done = false;
  do {
    { int p = L[a]; while (p != a) { int gp = L[p]; L[a] = gp; a = gp; p = L[a]; } }
    { int p = L[b]; while (p != b) { int gp = L[p]; L[b] = gp; b = gp; p = L[b]; } }
    if (a < b) {
      int old = atomicMin(&L[b], a);
      done = (old == b);
      b = old;
    } else if (b < a) {
      int old = atomicMin(&L[a], b);
      done = (old == a);
      a = old;
    } else {
      done = true;
    }
  } while (!done);
}

// run start bit (within 64-px segment) for a pixel at bit k of word w
__device__ __forceinline__ int runstart_bit(u64 w, int k) {
  u64 lowz = ~w & ((k == 0) ? 0ull : ((1ull << k) - 1));
  return lowz ? (64 - __clzll(lowz)) : 0;   // highest zero below k, +1
}

// ------------- bitmaps: [lvl][src][img][WPI] u64 words, 1 bit/px -----------

__global__ void k_base_mask_bits(const float* __restrict__ pred, const int* __restrict__ tgt,
                                 u64* __restrict__ bm) {
  int i = blockIdx.x * blockDim.x + threadIdx.x;   // over BB*HW
  if (i >= BB * HW) return;
  int b  = i >> 18;
  int hw = i & (HW - 1);
  float p0 = pred[(b * CC + 0) * HW + hw];
  float p1 = pred[(b * CC + 1) * HW + hw];
  float p2 = pred[(b * CC + 2) * HW + hw];
  float p3 = pred[(b * CC + 3) * HW + hw];
  int amax = 0; float best = p0;
  if (p1 > best) { best = p1; amax = 1; }
  if (p2 > best) { best = p2; amax = 2; }
  if (p3 > best) { best = p3; amax = 3; }
  int tg = tgt[i];
  int lane = threadIdx.x & 63;
  u64* bp = bm + (size_t)(2 * NSRC + 0) * NIMG * WPI;   // lvl2, src0
  u64* bt = bm + (size_t)(2 * NSRC + 1) * NIMG * WPI;   // lvl2, src1
#pragma unroll
  for (int c = 0; c < CC; ++c) {
    u64 wp = __ballot(amax == c);
    u64 wt = __ballot(tg == c);
    if (lane == 0) {
      int wi = ((b * CC + c) << 12) + (hw >> 6);
      bp[wi] = wp;
      bt[wi] = wt;
    }
  }
}

// 3x3 box morphology on bitmaps (both srcs of one level), zero padding.
__global__ void k_morph_bits(const u64* __restrict__ in, u64* __restrict__ out, int erode) {
  int t = blockIdx.x * blockDim.x + threadIdx.x;   // over NSRC*NIMG*WPI
  if (t >= NSRC * NIMG * WPI) return;
  int word = t & (WPI - 1);
  int row = word >> 3, wc = word & 7;
  const u64* ip = in + (t - word);
  u64 c0 = ip[word];
  u64 cm = wc ? ip[word - 1] : 0;
  u64 cp = (wc < 7) ? ip[word + 1] : 0;
  u64 u0 = 0, um = 0, up_ = 0, d0 = 0, dm = 0, dp = 0;
  if (row) {
    u0 = ip[word - 8];
    um = wc ? ip[word - 9] : 0;
    up_ = (wc < 7) ? ip[word - 7] : 0;
  }
  if (row < HHH - 1) {
    d0 = ip[word + 8];
    dm = wc ? ip[word + 7] : 0;
    dp = (wc < 7) ? ip[word + 9] : 0;
  }
  u64 v, vm, vp, r;
  if (erode) {
    v = u0 & c0 & d0; vm = um & cm & dm; vp = up_ & cp & dp;
    r = v & ((v << 1) | (vm >> 63)) & ((v >> 1) | (vp << 63));
  } else {
    v = u0 | c0 | d0; vm = um | cm | dm; vp = up_ | cp | dp;
    r = v | (v << 1) | (vm >> 63) | (v >> 1) | (vp << 63);
  }
  out[t] = r;
}

// -------- CCL phase A (batched over 5 levels): per-tile UF in LDS ----------
// Publishes labels ONLY at run-head pixels. Fuses hist/lcount zeroing and,
// when zc!=0 (first batch), the counts zeroing (poison kill).

__global__ __launch_bounds__(1024) void k_ccl_tile(const u64* __restrict__ bm, int src, int zc,
                                                   int* __restrict__ labels,
                                                   int* __restrict__ counts,
                                                   int* __restrict__ hist,
                                                   int* __restrict__ lcount) {
  __shared__ int par[TPX];          // 64 KB -> 2 blocks/CU
  __shared__ u64 w[TWORDS];         // 2 KB
  __shared__ int anyfg;
  int t = threadIdx.x;              // 1024
  int tile = blockIdx.x;            // NLVL*NIMG*NTILE = 1280
  int lvl = tile >> 8;
  int img = (tile >> 4) & 15;
  int tin = tile & 15;
  int bimg = tile >> 4;             // lvl*16+img, 0..79
  int trow0 = tin * TROWS;
  const u64* ib = bm + ((size_t)((lvl * NSRC + src) * NIMG + img) << 12);
  if (t == 0) anyfg = 0;
  __syncthreads();
  if (t < TWORDS) {
    u64 wd = ib[trow0 * 8 + t];
    w[t] = wd;
    if (wd) atomicOr(&anyfg, 1);
  }
  // fused zeroing
  if (t < 256) hist[bimg * NBIN + tin * 256 + t] = 0;
  if (t == 0 && tin == 0) lcount[bimg] = 0;
  if (zc) {
    int4* c4 = (int4*)(counts + (bimg << 18) + tin * TPX);
#pragma unroll
    for (int k = 0; k < TPX / 4096; ++k) c4[t + k * 1024] = make_int4(0, 0, 0, 0);
  }
  __syncthreads();
  if (!anyfg) return;               // empty tile: nothing to label
  // init: fg px -> its segment-run head; bg -> self (never read)
  for (int p = t; p < TPX; p += 1024) {
    u64 wd = w[p >> 6];
    int k = p & 63;
    par[p] = ((wd >> k) & 1) ? ((p & ~63) + runstart_bit(wd, k)) : p;
  }
  __syncthreads();
  // intra-tile unites: one wave per word, one lane per need-bit (LDS atomics)
  int wave = t >> 6, lane = t & 63;
  for (int i = wave; i < TWORDS; i += 16) {
    u64 r0 = w[i];
    if (!r0) continue;
    int row = i >> 3, wc = i & 7;
    int segbase = (row << 9) + (wc << 6);
    u64 prev = wc ? w[i - 1] : 0;
    if (lane == 0 && (r0 & 1) && (prev >> 63))
      unite(par, segbase, segbase - 64 + runstart_bit(prev, 63));
    if (row) {
      u64 up = w[i - 8];
      if (up) {
        u64 upprev = wc ? w[i - 9] : 0;
        u64 lsr0 = (r0 << 1) | (prev >> 63);
        u64 lsup = (up << 1) | (upprev >> 63);
        u64 need = r0 & up & ~(lsr0 & lsup);
        if ((need >> lane) & 1)
          unite(par, segbase + runstart_bit(r0, lane),
                     segbase - 512 + runstart_bit(up, lane));
      }
    }
  }
  __syncthreads();
  // flatten + publish HEADS ONLY (read-only walk; store to own global entry)
  int* L = labels + (bimg << 18) + trow0 * WWW;
  int off = trow0 * WWW;
  for (int i = wave; i < TWORDS; i += 16) {
    u64 wd = w[i];
    if (!wd) continue;
    u64 hm = wd & ~(wd << 1);
    if ((hm >> lane) & 1) {
      int p = ((i >> 3) << 9) + ((i & 7) << 6) + lane;
      int r = par[p];
      int q = par[r];
      while (q != r) { r = q; q = par[r]; }
      L[p] = off + r;
    }
  }
}

// -------- CCL phase B (batched): global unites across the 15 row-seams -----

__global__ void k_seam_merge(const u64* __restrict__ bm, int src, int* __restrict__ labels) {
  int gid = blockIdx.x * blockDim.x + threadIdx.x;
  int sw = gid >> 6;                 // seam-word id over NLVL*NIMG*NSEAM*8 = 9600
  if (sw >= NLVL * NIMG * NSEAM * 8) return;
  int lane = threadIdx.x & 63;
  int lvl = sw / (NIMG * NSEAM * 8);
  int rem = sw - lvl * (NIMG * NSEAM * 8);
  int img = rem / (NSEAM * 8);
  int rem2 = rem - img * (NSEAM * 8);
  int seam = rem2 >> 3, wc = rem2 & 7;
  int rowb = (seam + 1) * TROWS;     // top row of the lower tile
  const u64* ib = bm + ((size_t)((lvl * NSRC + src) * NIMG + img) << 12);
  int wb = rowb * 8 + wc;
  u64 r0 = ib[wb];
  if (!r0) return;
  u64 up = ib[wb - 8];
  if (!up) return;
  u64 prev = wc ? ib[wb - 1] : 0;
  u64 upprev = wc ? ib[wb - 9] : 0;
  u64 lsr0 = (r0 << 1) | (prev >> 63);
  u64 lsup = (up << 1) | (upprev >> 63);
  u64 need = r0 & up & ~(lsr0 & lsup);
  if ((need >> lane) & 1) {
    int* L = labels + ((lvl * NIMG + img) << 18);
    int segbase = (rowb << 9) + (wc << 6);
    unite(L, segbase + runstart_bit(r0, lane), segbase - 512 + runstart_bit(up, lane));
  }
}

// Fused flatten+count (batched): head lanes walk the near-flat chain
// read-only, run length from bits, LDS-hash dedupe, one atomic per root/block.
__global__ void k_flatten_count(const u64* __restrict__ bm, int src,
                                const int* __restrict__ labels, int* __restrict__ counts) {
  __shared__ int hk[HSZ];
  __shared__ int hv[HSZ];
  int t = threadIdx.x;               // 1024
  if (t < HSZ) { hk[t] = -1; hv[t] = 0; }
  __syncthreads();
  int g = blockIdx.x * 1024 + t;     // batch pixel id over NB*HW
  int bimg = g >> 18;
  int lvl = bimg >> 4;
  int lane = t & 63;
  const u64* ib = bm + ((size_t)((lvl * NSRC + src) * NIMG + (bimg & 15)) << 12);
  u64 w = ib[(g & (HW - 1)) >> 6];
  const int* L = labels + (bimg << 18);
  int hw = g & (HW - 1);
  u64 hm = w & ~(w << 1);
  if ((hm >> lane) & 1) {
    u64 inv = ~(w >> lane);
    int len = inv ? (__ffsll(inv) - 1) : (64 - lane);
    int r = hw;                      // read-only root walk from the head
    int q = L[r];
    while (q != r) { r = q; q = L[r]; }
    unsigned h = ((unsigned)r * 2654435761u >> 16) & (HSZ - 1);
    for (;;) {
      int prevk = atomicCAS(&hk[h], -1, r);
      if (prevk == -1 || prevk == r) { atomicAdd(&hv[h], len); break; }
      h = (h + 1) & (HSZ - 1);
    }
  }
  __syncthreads();
  int imgbase = (blockIdx.x * 1024) & ~(HW - 1);
  if (t < HSZ && hk[t] != -1)
    atomicAdd(&counts[imgbase + hk[t]], hv[t]);
}

// Head-gated histogram (batched) with counts SELF-RESET (keeps the buffer
// clean for the next batch/launch without a 80 MB memset).
__global__ void k_ccl_hist(const u64* __restrict__ bm, int src, int* __restrict__ counts,
                           int* __restrict__ hist, int* __restrict__ lcount,
                           int* __restrict__ lsizes) {
  __shared__ int lh[NBIN];
  int t = threadIdx.x;               // 1024
  for (int b = t; b < NBIN; b += 1024) lh[b] = 0;
  __syncthreads();
  int base = blockIdx.x * 16384;     // 16 blocks per image
  int bimg = base >> 18;
  int lvl = bimg >> 4;
  const u64* ib = bm + ((size_t)((lvl * NSRC + src) * NIMG + (bimg & 15)) << 12);
  int lane = t & 63;
#pragma unroll
  for (int j = 0; j < 16; ++j) {
    int g = base + t + j * 1024;
    u64 w = ib[(g & (HW - 1)) >> 6];
    if (!w) continue;
    u64 hm = w & ~(w << 1);
    if ((hm >> lane) & 1) {
      int s = counts[g];
      if (s > 0) {
        counts[g] = 0;               // self-reset
        if (s <= NBIN) atomicAdd(&lh[s - 1], 1);
        else {
          int idx = atomicAdd(&lcount[bimg], 1);
          if (idx < KTOP) lsizes[bimg * KTOP + idx] = s;
        }
      }
    }
  }
  __syncthreads();
  int* gh = hist + bimg * NBIN;
  for (int b = t; b < NBIN; b += 1024)
    if (lh[b]) atomicAdd(&gh[b], lh[b]);
}

// sorted top-64 per batch image: rank-sort the large list, then suffix-walk
// the 4096-bin LDS-resident histogram.
__global__ void k_top64(const int* __restrict__ hist, const int* __restrict__ lcount,
                        const int* __restrict__ lsizes, float* __restrict__ top, int src) {
  __shared__ int lh[NBIN];
  __shared__ int ls[KTOP];
  __shared__ int sc[256];
  int bimg = blockIdx.x;             // 0..79
  int t = threadIdx.x;               // 256
  const int* gh = hist + bimg * NBIN;
  for (int k = t; k < NBIN; k += 256) lh[k] = gh[k];
  int n = lcount[bimg];
  if (n > KTOP) n = KTOP;
  if (t < KTOP) ls[t] = (t < n) ? lsizes[bimg * KTOP + t] : 0;
  int lvl = bimg >> 4, im = bimg & 15;
  float* tp = top + ((size_t)(src * NLVL + lvl) * NIMG + im) * KTOP;
  if (t < KTOP) tp[t] = 0.f;
  __syncthreads();
  if (t < n) {                       // rank-sort descending (n <= 63)
    int myv = ls[t], rank = 0;
    for (int j = 0; j < n; ++j) {
      int vj = ls[j];
      rank += (vj > myv) || (vj == myv && j < t);
    }
    tp[rank] = (float)myv;
  }
  int base = NBIN - 16 * (t + 1);    // descending chunks of 16 bins
  int c = 0;
#pragma unroll
  for (int k = 0; k < 16; ++k) c += lh[base + k];
  sc[t] = c;
  __syncthreads();
  for (int off = 1; off < 256; off <<= 1) {
    int v = (t >= off) ? sc[t - off] : 0;
    __syncthreads();
    sc[t] += v;
    __syncthreads();
  }
  int pos = n + sc[t] - c;
  if (pos < KTOP && c > 0) {
    for (int k = 15; k >= 0 && pos < KTOP; --k) {
      int s = base + k + 1;
      int hc = lh[base + k];
      while (hc-- > 0 && pos < KTOP) tp[pos++] = (float)s;
    }
  }
}

// loss[b] = sum over {lvl, c, k} |topP - topT| ; top layout [src][lvl][img][KTOP]
__global__ void k_loss(const float* __restrict__ top, float* __restrict__ out) {
  int b = blockIdx.x;
  int t = threadIdx.x;               // 256
  float acc = 0.f;
  const int TOT = NLVL * CC * KTOP;  // 1280
  for (int e = t; e < TOT; e += 256) {
    int k = e & (KTOP - 1);
    int rest = e >> 6;
    int c = rest & (CC - 1);
    int lvl = rest >> 2;
    int img = b * CC + c;
    size_t iP = ((size_t)(0 * NLVL + lvl) * NIMG + img) * KTOP + k;
    size_t iT = ((size_t)(1 * NLVL + lvl) * NIMG + img) * KTOP + k;
    acc += fabsf(top[iP] - top[iT]);
  }
  __shared__ float r[256];
  r[t] = acc;
  __syncthreads();
  for (int off = 128; off > 0; off >>= 1) {
    if (t < off) r[t] += r[t + off];
    __syncthreads();
  }
  if (t == 0) out[b] = r[0];
}

// ---------------- driver: 16 dispatches total ----------------

extern "C" void kernel_launch(void* const* d_in, const int* in_sizes, int n_in,
                              void* d_out, int out_size, void* d_ws, size_t ws_size,
                              hipStream_t stream) {
  const float* pred = (const float*)d_in[0];
  const int*   tgt  = (const int*)d_in[1];
  float* out = (float*)d_out;

  uint8_t* ws = (uint8_t*)d_ws;
  size_t off = 0;
  u64* bmAll  = (u64*)(ws + off); off += (size_t)NLVL * NSRC * NIMG * WPI * 8;  // 5 MB
  int* labels = (int*)(ws + off); off += (size_t)NB * HW * 4;                   // 80 MB
  int* counts = (int*)(ws + off); off += (size_t)NB * HW * 4;                   // 80 MB
  int* hist   = (int*)(ws + off); off += (size_t)NB * NBIN * 4;                 // 1.25 MB
  int* lcount = (int*)(ws + off); off += (size_t)NB * 4;
  int* lsizes = (int*)(ws + off); off += (size_t)NB * KTOP * 4;
  float* top  = (float*)(ws + off); off += (size_t)NSRC * NLVL * NIMG * KTOP * 4;

  const size_t S = (size_t)NSRC * NIMG * WPI;      // words per level slice
  const int MW = NSRC * NIMG * WPI;                // morphology threads (131072)

  // 1) all 10 bitmaps: base (lvl 2), erosions (3,4), dilations (1,0)
  k_base_mask_bits<<<(BB * HW) / 256, 256, 0, stream>>>(pred, tgt, bmAll);
  k_morph_bits<<<MW / 256, 256, 0, stream>>>(bmAll + 2 * S, bmAll + 3 * S, 1);
  k_morph_bits<<<MW / 256, 256, 0, stream>>>(bmAll + 3 * S, bmAll + 4 * S, 1);
  k_morph_bits<<<MW / 256, 256, 0, stream>>>(bmAll + 2 * S, bmAll + 1 * S, 0);
  k_morph_bits<<<MW / 256, 256, 0, stream>>>(bmAll + 1 * S, bmAll + 0 * S, 0);

  // 2) batched CCL: one 5-kernel pipeline per source over all 5 levels
  for (int src = 0; src < NSRC; ++src) {
    k_ccl_tile     <<<NLVL * NIMG * NTILE, 1024, 0, stream>>>(bmAll, src, src == 0 ? 1 : 0,
                                                              labels, counts, hist, lcount);
    k_seam_merge   <<<(NLVL * NIMG * NSEAM * 8 * 64) / 256, 256, 0, stream>>>(bmAll, src, labels);
    k_flatten_count<<<(NB * HW) / 1024, 1024, 0, stream>>>(bmAll, src, labels, counts);
    k_ccl_hist     <<<(NB * HW) / 16384, 1024, 0, stream>>>(bmAll, src, counts, hist, lcount, lsizes);
    k_top64        <<<NB, 256, 0, stream>>>(hist, lcount, lsizes, top, src);
  }

  // 3) loss
  k_loss<<<BB, 256, 0, stream>>>(top, out);
}

// Round 10
// 291.032 us; speedup vs baseline: 3.2332x; 1.2786x over previous
//
#include <hip/hip_runtime.h>
#include <stdint.h>

typedef unsigned long long u64;

#define BB   4
#define CC   4
#define HHH  512
#define WWW  512
#define HW   (HHH*WWW)        /* 262144 = 2^18 */
#define NIMG (BB*CC)          /* 16 */
#define NSRC 2
#define NLVL 5
#define NB   (NLVL*NIMG)      /* 80 images per src batch */
#define KTOP 64
#define NBIN 4096             /* histogram bins; sizes > NBIN go to the large list (<=63) */
#define WPI  4096             /* 64-bit words per image (512 rows * 8) */
#define TROWS 32              /* tile = 32 rows x 512 cols -> 64 KB par, 2 blocks/CU */
#define TPX  (TROWS*WWW)      /* 16384 px per tile */
#define TWORDS (TROWS*8)      /* 256 words per tile */
#define NTILE 16              /* tiles per image */
#define NSEAM (NTILE-1)       /* 15 row-seams per image */
#define RCAP 8192             /* max roots per tile (checkerboard bound) */
#define NSUB 4                /* LDS histogram sub-banks */

// ---------------- union-find (min-root == min pixel index) ----------------
// Convergence test uses ONLY atomic return values; path-halving plain stores
// always write a valid ancestor (values monotone decreasing).

__device__ __forceinline__ void unite(int* L, int a, int b) {
  bool done = false;
  do {
    { int p = L[a]; while (p != a) { int gp = L[p]; L[a] = gp; a = gp; p = L[a]; } }
    { int p = L[b]; while (p != b) { int gp = L[p]; L[b] = gp; b = gp; p = L[b]; } }
    if (a < b) {
      int old = atomicMin(&L[b], a);
      done = (old == b);
      b = old;
    } else if (b < a) {
      int old = atomicMin(&L[a], b);
      done = (old == a);
      a = old;
    } else {
      done = true;
    }
  } while (!done);
}

// run start bit (within 64-px segment) for a pixel at bit k of word w
__device__ __forceinline__ int runstart_bit(u64 w, int k) {
  u64 lowz = ~w & ((k == 0) ? 0ull : ((1ull << k) - 1));
  return lowz ? (64 - __clzll(lowz)) : 0;   // highest zero below k, +1
}

// ------------- bitmaps: [lvl][src][img][WPI] u64 words, 1 bit/px -----------

__global__ void k_base_mask_bits(const float* __restrict__ pred, const int* __restrict__ tgt,
                                 u64* __restrict__ bm) {
  int i = blockIdx.x * blockDim.x + threadIdx.x;   // over BB*HW
  if (i >= BB * HW) return;
  int b  = i >> 18;
  int hw = i & (HW - 1);
  float p0 = pred[(b * CC + 0) * HW + hw];
  float p1 = pred[(b * CC + 1) * HW + hw];
  float p2 = pred[(b * CC + 2) * HW + hw];
  float p3 = pred[(b * CC + 3) * HW + hw];
  int amax = 0; float best = p0;
  if (p1 > best) { best = p1; amax = 1; }
  if (p2 > best) { best = p2; amax = 2; }
  if (p3 > best) { best = p3; amax = 3; }
  int tg = tgt[i];
  int lane = threadIdx.x & 63;
  u64* bp = bm + (size_t)(2 * NSRC + 0) * NIMG * WPI;   // lvl2, src0
  u64* bt = bm + (size_t)(2 * NSRC + 1) * NIMG * WPI;   // lvl2, src1
#pragma unroll
  for (int c = 0; c < CC; ++c) {
    u64 wp = __ballot(amax == c);
    u64 wt = __ballot(tg == c);
    if (lane == 0) {
      int wi = ((b * CC + c) << 12) + (hw >> 6);
      bp[wi] = wp;
      bt[wi] = wt;
    }
  }
}

// 3x3 box morphology on bitmaps (both srcs of one level), zero padding.
__global__ void k_morph_bits(const u64* __restrict__ in, u64* __restrict__ out, int erode) {
  int t = blockIdx.x * blockDim.x + threadIdx.x;   // over NSRC*NIMG*WPI
  if (t >= NSRC * NIMG * WPI) return;
  int word = t & (WPI - 1);
  int row = word >> 3, wc = word & 7;
  const u64* ip = in + (t - word);
  u64 c0 = ip[word];
  u64 cm = wc ? ip[word - 1] : 0;
  u64 cp = (wc < 7) ? ip[word + 1] : 0;
  u64 u0 = 0, um = 0, up_ = 0, d0 = 0, dm = 0, dp = 0;
  if (row) {
    u0 = ip[word - 8];
    um = wc ? ip[word - 9] : 0;
    up_ = (wc < 7) ? ip[word - 7] : 0;
  }
  if (row < HHH - 1) {
    d0 = ip[word + 8];
    dm = wc ? ip[word + 7] : 0;
    dp = (wc < 7) ? ip[word + 9] : 0;
  }
  u64 v, vm, vp, r;
  if (erode) {
    v = u0 & c0 & d0; vm = um & cm & dm; vp = up_ & cp & dp;
    r = v & ((v << 1) | (vm >> 63)) & ((v >> 1) | (vp << 63));
  } else {
    v = u0 | c0 | d0; vm = um | cm | dm; vp = up_ | cp | dp;
    r = v | (v << 1) | (vm >> 63) | (v >> 1) | (vp << 63);
  }
  out[t] = r;
}

// -------- CCL phase A (batched): per-tile UF + per-root SIZES in LDS --------
// par[] encoding after flatten: low 14 bits = local root idx, bits >=14 = size
// accumulated at root entries (root<16384, size<=16384 -> fits int).
// Emits: labels at heads (global), counts[root]=size (plain store, no zeroing
// needed), compact per-tile root list.

__global__ __launch_bounds__(1024) void k_ccl_tile(const u64* __restrict__ bm, int src,
                                                   int* __restrict__ labels,
                                                   int* __restrict__ counts,
                                                   int* __restrict__ rootbuf,
                                                   int* __restrict__ rootcnt) {
  __shared__ int par[TPX];          // 64 KB -> 2 blocks/CU
  __shared__ u64 w[TWORDS];         // 2 KB
  __shared__ int anyfg, rc;
  int t = threadIdx.x;              // 1024
  int tile = blockIdx.x;            // NLVL*NIMG*NTILE = 1280
  int lvl = tile >> 8;
  int img = (tile >> 4) & 15;
  int tin = tile & 15;
  int bimg = tile >> 4;             // 0..79
  int trow0 = tin * TROWS;
  const u64* ib = bm + ((size_t)((lvl * NSRC + src) * NIMG + img) << 12);
  if (t == 0) { anyfg = 0; rc = 0; }
  __syncthreads();
  if (t < TWORDS) {
    u64 wd = ib[trow0 * 8 + t];
    w[t] = wd;
    if (wd) atomicOr(&anyfg, 1);
  }
  __syncthreads();
  if (!anyfg) { if (t == 0) rootcnt[tile] = 0; return; }
  // init: fg px -> its segment-run head; bg -> self (never read)
  for (int p = t; p < TPX; p += 1024) {
    u64 wd = w[p >> 6];
    int k = p & 63;
    par[p] = ((wd >> k) & 1) ? ((p & ~63) + runstart_bit(wd, k)) : p;
  }
  __syncthreads();
  // intra-tile unites: one wave per word, one lane per need-bit (LDS atomics)
  int wave = t >> 6, lane = t & 63;
  for (int i = wave; i < TWORDS; i += 16) {
    u64 r0 = w[i];
    if (!r0) continue;
    int row = i >> 3, wc = i & 7;
    int segbase = (row << 9) + (wc << 6);
    u64 prev = wc ? w[i - 1] : 0;
    if (lane == 0 && (r0 & 1) && (prev >> 63))
      unite(par, segbase, segbase - 64 + runstart_bit(prev, 63));
    if (row) {
      u64 up = w[i - 8];
      if (up) {
        u64 upprev = wc ? w[i - 9] : 0;
        u64 lsr0 = (r0 << 1) | (prev >> 63);
        u64 lsup = (up << 1) | (upprev >> 63);
        u64 need = r0 & up & ~(lsr0 & lsup);
        if ((need >> lane) & 1)
          unite(par, segbase + runstart_bit(r0, lane),
                     segbase - 512 + runstart_bit(up, lane));
      }
    }
  }
  __syncthreads();
  // phase F: flatten heads (read-only walk), publish global labels, and store
  // each head's root into its OWN par entry (benign: a valid ancestor).
  int off = trow0 * WWW;
  int* L = labels + (bimg << 18) + off;
  for (int i = wave; i < TWORDS; i += 16) {
    u64 wd = w[i];
    if (!wd) continue;
    u64 hm = wd & ~(wd << 1);
    if ((hm >> lane) & 1) {
      int p = ((i >> 3) << 9) + ((i & 7) << 6) + lane;
      int r = par[p];
      int q = par[r];
      while (q != r) { r = q; q = par[r]; }
      L[p] = off + r;
      par[p] = r;
    }
  }
  __syncthreads();
  // phase A: accumulate run lengths into root entries' HIGH bits (len<<14);
  // low 14 bits (root idx) unaffected since addend's low 14 bits are 0.
  for (int i = wave; i < TWORDS; i += 16) {
    u64 wd = w[i];
    if (!wd) continue;
    u64 hm = wd & ~(wd << 1);
    if ((hm >> lane) & 1) {
      int p = ((i >> 3) << 9) + ((i & 7) << 6) + lane;
      u64 inv = ~(wd >> lane);
      int len = inv ? (__ffsll(inv) - 1) : (64 - lane);
      int r = par[p] & 16383;
      atomicAdd(&par[r], len << 14);
    }
  }
  __syncthreads();
  // phase S: emit tile roots (size>0 and self-pointing low bits)
  int base = bimg << 18;
  for (int p = t; p < TPX; p += 1024) {
    int v = par[p];
    int sz = v >> 14;
    if (sz > 0 && (v & 16383) == p) {
      int idx = atomicAdd(&rc, 1);
      rootbuf[tile * RCAP + idx] = off + p;
      counts[base + off + p] = sz;
    }
  }
  __syncthreads();
  if (t == 0) rootcnt[tile] = rc;
}

// -------- CCL phase B (batched): global unites across the 15 row-seams -----

__global__ void k_seam_merge(const u64* __restrict__ bm, int src, int* __restrict__ labels) {
  int gid = blockIdx.x * blockDim.x + threadIdx.x;
  int sw = gid >> 6;                 // seam-word id over NLVL*NIMG*NSEAM*8 = 9600
  if (sw >= NLVL * NIMG * NSEAM * 8) return;
  int lane = threadIdx.x & 63;
  int lvl = sw / (NIMG * NSEAM * 8);
  int rem = sw - lvl * (NIMG * NSEAM * 8);
  int img = rem / (NSEAM * 8);
  int rem2 = rem - img * (NSEAM * 8);
  int seam = rem2 >> 3, wc = rem2 & 7;
  int rowb = (seam + 1) * TROWS;     // top row of the lower tile
  const u64* ib = bm + ((size_t)((lvl * NSRC + src) * NIMG + img) << 12);
  int wb = rowb * 8 + wc;
  u64 r0 = ib[wb];
  if (!r0) return;
  u64 up = ib[wb - 8];
  if (!up) return;
  u64 prev = wc ? ib[wb - 1] : 0;
  u64 upprev = wc ? ib[wb - 9] : 0;
  u64 lsr0 = (r0 << 1) | (prev >> 63);
  u64 lsup = (up << 1) | (upprev >> 63);
  u64 need = r0 & up & ~(lsr0 & lsup);
  if ((need >> lane) & 1) {
    int* L = labels + ((lvl * NIMG + img) << 18);
    int segbase = (rowb << 9) + (wc << 6);
    unite(L, segbase + runstart_bit(r0, lane), segbase - 512 + runstart_bit(up, lane));
  }
}

// -------- fixup: fold non-global tile-root sizes into their global root -----
// Per tile-root r: walk labels (read-only) to global root g; if g != r, add
// counts[r] into counts[g]. Nobody adds into non-global entries, and reads of
// counts[g] happen only in the NEXT kernel -> race-free.

__global__ void k_fixup(const int* __restrict__ rootcnt, const int* __restrict__ rootbuf,
                        const int* __restrict__ labels, int* __restrict__ counts) {
  int tile = blockIdx.x;             // 1280
  int bimg = tile >> 4;
  int n = rootcnt[tile];
  const int* L = labels + (bimg << 18);
  int base = bimg << 18;
  for (int e = threadIdx.x; e < n; e += 256) {
    int r = rootbuf[tile * RCAP + e];
    int g = r;
    int q = L[g];
    while (q != g) { g = q; q = L[g]; }
    if (g != r) atomicAdd(&counts[base + g], counts[base + r]);
  }
}

// -------- fused histogram + sorted top-64, one block per batch image --------
// Iterates the image's 16 compact root lists; keeps only global roots
// (L[r]==r); 4-way sub-banked LDS hist cuts same-bin atomic contention.

__global__ __launch_bounds__(1024) void k_hist_top(const int* __restrict__ rootcnt,
                                                   const int* __restrict__ rootbuf,
                                                   const int* __restrict__ labels,
                                                   const int* __restrict__ counts,
                                                   float* __restrict__ top, int src) {
  __shared__ int lh[NSUB][NBIN];     // 64 KB
  __shared__ int sc[1024];
  __shared__ int ls[KTOP];
  __shared__ int lcnt;
  int bimg = blockIdx.x;             // 0..79
  int t = threadIdx.x;               // 1024
  for (int b = t; b < NSUB * NBIN; b += 1024) ((int*)lh)[b] = 0;
  if (t == 0) lcnt = 0;
  __syncthreads();
  const int* L = labels + (bimg << 18);
  const int* cnt = counts + (bimg << 18);
  int sub = (t >> 6) & (NSUB - 1);
  for (int tin = 0; tin < NTILE; ++tin) {
    int tile = bimg * NTILE + tin;
    int n = rootcnt[tile];
    for (int e = t; e < n; e += 1024) {
      int r = rootbuf[tile * RCAP + e];
      if (L[r] == r) {               // global root
        int s = cnt[r];
        if (s <= NBIN) atomicAdd(&lh[sub][s - 1], 1);
        else { int idx = atomicAdd(&lcnt, 1); if (idx < KTOP) ls[idx] = s; }
      }
    }
  }
  __syncthreads();
  // merge sub-hists into lh[0]
  for (int b = t; b < NBIN; b += 1024) {
    int s = lh[0][b];
#pragma unroll
    for (int u = 1; u < NSUB; ++u) s += lh[u][b];
    lh[0][b] = s;
  }
  int n = lcnt; if (n > KTOP) n = KTOP;   // n <= 63 mathematically
  int lvl = bimg >> 4, im = bimg & 15;
  float* tp = top + ((size_t)(src * NLVL + lvl) * NIMG + im) * KTOP;
  if (t < KTOP) tp[t] = 0.f;
  __syncthreads();                   // also orders merge-writes before reads below
  if (t < n) {                       // rank-sort descending large list
    int myv = ls[t], rank = 0;
    for (int j = 0; j < n; ++j) {
      int vj = ls[j];
      rank += (vj > myv) || (vj == myv && j < t);
    }
    tp[rank] = (float)myv;
  }
  int base = NBIN - 4 * (t + 1);     // descending chunks of 4 bins
  int c = lh[0][base] + lh[0][base + 1] + lh[0][base + 2] + lh[0][base + 3];
  sc[t] = c;
  __syncthreads();
  for (int off = 1; off < 1024; off <<= 1) {   // Hillis-Steele inclusive scan
    int v = (t >= off) ? sc[t - off] : 0;
    __syncthreads();
    sc[t] += v;
    __syncthreads();
  }
  int pos = n + sc[t] - c;           // components ranked before my chunk
  if (pos < KTOP && c > 0) {
    for (int k = 3; k >= 0 && pos < KTOP; --k) {
      int s = base + k + 1;
      int hc = lh[0][base + k];
      while (hc-- > 0 && pos < KTOP) tp[pos++] = (float)s;
    }
  }
}

// loss[b] = sum over {lvl, c, k} |topP - topT| ; top layout [src][lvl][img][KTOP]
__global__ void k_loss(const float* __restrict__ top, float* __restrict__ out) {
  int b = blockIdx.x;
  int t = threadIdx.x;               // 256
  float acc = 0.f;
  const int TOT = NLVL * CC * KTOP;  // 1280
  for (int e = t; e < TOT; e += 256) {
    int k = e & (KTOP - 1);
    int rest = e >> 6;
    int c = rest & (CC - 1);
    int lvl = rest >> 2;
    int img = b * CC + c;
    size_t iP = ((size_t)(0 * NLVL + lvl) * NIMG + img) * KTOP + k;
    size_t iT = ((size_t)(1 * NLVL + lvl) * NIMG + img) * KTOP + k;
    acc += fabsf(top[iP] - top[iT]);
  }
  __shared__ float r[256];
  r[t] = acc;
  __syncthreads();
  for (int off = 128; off > 0; off >>= 1) {
    if (t < off) r[t] += r[t + off];
    __syncthreads();
  }
  if (t == 0) out[b] = r[0];
}

// ---------------- driver: 14 dispatches total ----------------

extern "C" void kernel_launch(void* const* d_in, const int* in_sizes, int n_in,
                              void* d_out, int out_size, void* d_ws, size_t ws_size,
                              hipStream_t stream) {
  const float* pred = (const float*)d_in[0];
  const int*   tgt  = (const int*)d_in[1];
  float* out = (float*)d_out;

  uint8_t* ws = (uint8_t*)d_ws;
  size_t off = 0;
  u64* bmAll   = (u64*)(ws + off); off += (size_t)NLVL * NSRC * NIMG * WPI * 8;  // 5 MB
  int* labels  = (int*)(ws + off); off += (size_t)NB * HW * 4;                   // 80 MB
  int* counts  = (int*)(ws + off); off += (size_t)NB * HW * 4;                   // 80 MB
  int* rootbuf = (int*)(ws + off); off += (size_t)NB * NTILE * RCAP * 4;         // 40 MB
  int* rootcnt = (int*)(ws + off); off += (size_t)NB * NTILE * 4;
  float* top   = (float*)(ws + off); off += (size_t)NSRC * NLVL * NIMG * KTOP * 4;

  const size_t S = (size_t)NSRC * NIMG * WPI;      // words per level slice
  const int MW = NSRC * NIMG * WPI;                // morphology threads (131072)

  // 1) all 10 bitmaps: base (lvl 2), erosions (3,4), dilations (1,0)
  k_base_mask_bits<<<(BB * HW) / 256, 256, 0, stream>>>(pred, tgt, bmAll);
  k_morph_bits<<<MW / 256, 256, 0, stream>>>(bmAll + 2 * S, bmAll + 3 * S, 1);
  k_morph_bits<<<MW / 256, 256, 0, stream>>>(bmAll + 3 * S, bmAll + 4 * S, 1);
  k_morph_bits<<<MW / 256, 256, 0, stream>>>(bmAll + 2 * S, bmAll + 1 * S, 0);
  k_morph_bits<<<MW / 256, 256, 0, stream>>>(bmAll + 1 * S, bmAll + 0 * S, 0);

  // 2) batched CCL per source over all 5 levels
  for (int src = 0; src < NSRC; ++src) {
    k_ccl_tile <<<NB * NTILE, 1024, 0, stream>>>(bmAll, src, labels, counts, rootbuf, rootcnt);
    k_seam_merge<<<(NLVL * NIMG * NSEAM * 8 * 64) / 256, 256, 0, stream>>>(bmAll, src, labels);
    k_fixup    <<<NB * NTILE, 256, 0, stream>>>(rootcnt, rootbuf, labels, counts);
    k_hist_top <<<NB, 1024, 0, stream>>>(rootcnt, rootbuf, labels, counts, top, src);
  }

  // 3) loss
  k_loss<<<BB, 256, 0, stream>>>(top, out);
}